// Round 3
// baseline (147.185 us; speedup 1.0000x reference)
//
#include <hip/hip_runtime.h>
#include <hip/hip_bf16.h>
#include <stdint.h>

// ===================================================================
// PriorLayer online BP scan, round 5. s_t = norm(diag(p_t) T s_{t-1}).
// Evidence R1-R4: per-step ~4700cyc invariant under body size, wave
// count, block count; all pipes <30%; R3 showed two independent blocks
// on one CU overlap ZERO (in-order waves + convoy-correlated stalls =>
// scheduler can't fill latency). R4's wave-halving was confounded by
// 23MB of VGPR-spill traffic (WRITE_SIZE 90MB vs 67MB out).
// Fix: interleave TWO independent chains inside each wave's own
// instruction stream (ILP, no scheduler needed):
//  - NCH=2 chains x CLEN=8, 32 chunks/block, NBLK=256 (1/CU).
//  - kb-loop interleaves both chains: 4 independent MFMA dep chains;
//    chain Y issues under chain X's LDS/MFMA latency.
//  - ONE barrier per epoch orders BOTH chains (writeX,writeY,bar,
//    readX,readY) => barriers per time-step halved; 20 epochs vs 28.
//  - Back to R2's no-spill register shape: A[2][8]=64 regs, 2 row-
//    tiles/wave, 8 waves.
//  - Lane-private partials (valid R4 idea): each lane's 8 q-values are
//    one (w,quad) row-group => no cross-lane shuffles on the chain;
//    finalize sums 32 broadcast b64 reads, deferred one epoch.
//  - Keep: burn gating, nontemporal out stores, lgkmcnt-only barrier,
//    2-deep per-chain prefetch ring.
// ===================================================================

#define DIM   256
#define SEQ   65536
#define G     16                    // chunks (MFMA columns) per chain
#define NCH   2                     // chains per block
#define CLEN  8                     // output steps per chunk
#define NBLK  (SEQ / (G * NCH * CLEN))  // 256 blocks -> 1 per CU
#define BURN  12
#define STEPS (BURN + CLEN)         // 20 epochs (even — pairing)
#define NW    8
#define TPB   (NW * 64)             // 512
#define SROW  264                   // padded LDS row stride (bf16 elems)

typedef short bf16x8 __attribute__((ext_vector_type(8)));
typedef float f32x4  __attribute__((ext_vector_type(4)));
typedef float f32x2  __attribute__((ext_vector_type(2)));

static __device__ __forceinline__ unsigned short f2bf(float x) {
  __hip_bfloat16 h = __float2bfloat16(x);
  return *reinterpret_cast<unsigned short*>(&h);
}

// LDS-only barrier: do NOT drain vmcnt (global stores / prefetch loads
// stay in flight). lgkmcnt(0) orders all ds ops.
static __device__ __forceinline__ void lds_barrier() {
  asm volatile("s_waitcnt lgkmcnt(0)" ::: "memory");
  __builtin_amdgcn_s_barrier();
}

__global__ __launch_bounds__(TPB)
void prior_scan_kernel(const float* __restrict__ probs,
                       const float* __restrict__ tp,
                       float* __restrict__ out) {
  // S_T: per-chain double-buffered transposed state [chain][buf][chunk][row].
  // pZL: double-buffered lane partials [buf][chain][w*4+quad][chunk].
  __shared__ __attribute__((aligned(16))) short S_T[NCH][2][G][SROW];
  __shared__ __attribute__((aligned(16))) f32x2 pZL[2][NCH][32][G];

  const int tid  = threadIdx.x;
  const int w    = tid >> 6;
  const int lane = tid & 63;
  const int n    = lane & 15;       // MFMA col = chunk within chain
  const int quad = lane >> 4;
  const int cbase = blockIdx.x * (G * NCH);
  const int wq = w * 4 + quad;      // lane's row-group id (0..31)

  int rb[2];                        // C/D row bases, 2 row-tiles
  rb[0] = w * 32 + quad * 4;
  rb[1] = w * 32 + 16 + quad * 4;

  // ---- T into A-fragments: A[m=lane&15][k=quad*8+j]; row=w*32+rt*16+m
  bf16x8 A[2][8];
#pragma unroll
  for (int rt = 0; rt < 2; rt++) {
    const int row = w * 32 + rt * 16 + n;
#pragma unroll
    for (int kb = 0; kb < 8; kb++) {
      const float* p = tp + row * DIM + kb * 32 + quad * 8;
      f32x4 f0 = *reinterpret_cast<const f32x4*>(p);
      f32x4 f1 = *reinterpret_cast<const f32x4*>(p + 4);
      bf16x8 a;
#pragma unroll
      for (int j = 0; j < 4; j++) {
        a[j]     = (short)f2bf(f0[j]);
        a[4 + j] = (short)f2bf(f1[j]);
      }
      A[rt][kb] = a;
    }
  }

  // ---- init states (both chains) = uniform 1/256 (bf16-exact)
  for (int i = tid; i < NCH * 2 * G * SROW; i += TPB)
    (&S_T[0][0][0][0])[i] = (short)0x3B80;

  // ---- observation fragment loader (lane-owned, direct from global)
  auto loadp = [&](int c, int s, int rbase, bool clamp) -> f32x4 {
    int t = (cbase + c * G + n) * CLEN - BURN + s;
    if (clamp && t < 0) t = 0;      // value unused when t<0
    return *reinterpret_cast<const f32x4*>(probs + (size_t)t * DIM + rbase);
  };

  // 2-deep register prefetch ring per chain
  f32x4 pf[2][NCH][2];
#pragma unroll
  for (int c = 0; c < NCH; c++)
#pragma unroll
    for (int rt = 0; rt < 2; rt++) {
      pf[0][c][rt] = loadp(c, 0, rb[rt], true);
      pf[1][c][rt] = loadp(c, 1, rb[rt], true);
    }

  lds_barrier();

  float qp[NCH][2][4];              // q of previous epoch (deferred norm)

  // --- both chains' matvecs, kb-interleaved: 4 independent MFMA chains
  auto matvec2 = [&](int cur, float (&q)[NCH][2][4]) {
    f32x4 a00 = {0.f,0.f,0.f,0.f}, a01 = {0.f,0.f,0.f,0.f};
    f32x4 a10 = {0.f,0.f,0.f,0.f}, a11 = {0.f,0.f,0.f,0.f};
#pragma unroll
    for (int kb = 0; kb < 8; kb++) {
      bf16x8 b0 = *reinterpret_cast<const bf16x8*>(
          &S_T[0][cur][n][kb * 32 + quad * 8]);
      bf16x8 b1 = *reinterpret_cast<const bf16x8*>(
          &S_T[1][cur][n][kb * 32 + quad * 8]);
      a00 = __builtin_amdgcn_mfma_f32_16x16x32_bf16(A[0][kb], b0, a00, 0, 0, 0);
      a01 = __builtin_amdgcn_mfma_f32_16x16x32_bf16(A[1][kb], b0, a01, 0, 0, 0);
      a10 = __builtin_amdgcn_mfma_f32_16x16x32_bf16(A[0][kb], b1, a10, 0, 0, 0);
      a11 = __builtin_amdgcn_mfma_f32_16x16x32_bf16(A[1][kb], b1, a11, 0, 0, 0);
    }
#pragma unroll
    for (int v = 0; v < 4; v++) {
      q[0][0][v] = a00[v] * pf[cur][0][0][v];   // row=quad*4+v (+tile), col=n
      q[0][1][v] = a01[v] * pf[cur][0][1][v];
      q[1][0][v] = a10[v] * pf[cur][1][0][v];
      q[1][1][v] = a11[v] * pf[cur][1][1][v];
    }
  };

  auto write_state = [&](int c, int nxt, const float (&q)[2][4]) {
#pragma unroll
    for (int rt = 0; rt < 2; rt++) {
      ushort4 sp;
      sp.x = f2bf(q[rt][0] * 0.015625f);
      sp.y = f2bf(q[rt][1] * 0.015625f);
      sp.z = f2bf(q[rt][2] * 0.015625f);
      sp.w = f2bf(q[rt][3] * 0.015625f);
      *reinterpret_cast<ushort4*>(&S_T[c][nxt][n][rb[rt]]) = sp;
    }
  };

  // --- burn epoch: NO partials, NO finalize, NO qp carry
  auto burn_body = [&](int e, int cur, int nxt) {
    float q[NCH][2][4];
    matvec2(cur, q);
#pragma unroll
    for (int c = 0; c < NCH; c++) {
      const int t = (cbase + c * G + n) * CLEN - BURN + e;
      if (t < 0) {                  // pre-start: hold uniform state
        ushort4 sp;
        sp.x = sp.y = sp.z = sp.w = (unsigned short)0x3B80;
        *reinterpret_cast<ushort4*>(&S_T[c][nxt][n][rb[0]]) = sp;
        *reinterpret_cast<ushort4*>(&S_T[c][nxt][n][rb[1]]) = sp;
      } else {
        write_state(c, nxt, q[c]);
      }
    }
#pragma unroll
    for (int c = 0; c < NCH; c++)
#pragma unroll
      for (int rt = 0; rt < 2; rt++)
        pf[cur][c][rt] = loadp(c, e + 2, rb[rt], true);  // e+2 <= BURN+1
    lds_barrier();
  };

  // --- output epoch: lane-private partials + deferred finalize of e-1
  auto main_body = [&](int e, int cur, int nxt) {
    float q[NCH][2][4];
    matvec2(cur, q);
#pragma unroll
    for (int c = 0; c < NCH; c++)
      write_state(c, nxt, q[c]);    // LDS writes early (on the chain)

    // lane-private partials over this lane's 8 rows (no cross-lane ops)
#pragma unroll
    for (int c = 0; c < NCH; c++) {
      float sz = 0.f, sl = 0.f;
#pragma unroll
      for (int rt = 0; rt < 2; rt++)
#pragma unroll
        for (int v = 0; v < 4; v++) {
          float qq = q[c][rt][v];
          sz += qq;
          sl += qq * __logf(qq + 1e-30f);
        }
      pZL[cur][c][wq][n] = f32x2{sz, sl};
    }

    if (e > BURN) {                 // deferred finalize of epoch e-1
#pragma unroll
      for (int c = 0; c < NCH; c++) {
        float Z = 0.f, L = 0.f;
#pragma unroll
        for (int g = 0; g < 32; g++) {
          f32x2 v = pZL[nxt][c][g][n];   // nxt == (e-1)&1
          Z += v[0]; L += v[1];
        }
        const float zi = __builtin_amdgcn_rcpf(Z);
        const int t1 = (cbase + c * G + n) * CLEN + (e - 1 - BURN);
#pragma unroll
        for (int rt = 0; rt < 2; rt++) {
          f32x4 o;
#pragma unroll
          for (int v = 0; v < 4; v++) o[v] = qp[c][rt][v] * zi;
          __builtin_nontemporal_store(
              o, reinterpret_cast<f32x4*>(out + (size_t)t1 * DIM + rb[rt]));
        }
        if (lane < 16 && w == c * 4)     // n == lane for these lanes
          __builtin_nontemporal_store(__logf(Z) - L * zi,
                                      out + (size_t)SEQ * DIM + t1);
      }
    }

#pragma unroll
    for (int c = 0; c < NCH; c++)
#pragma unroll
      for (int rt = 0; rt < 2; rt++)
#pragma unroll
        for (int v = 0; v < 4; v++) qp[c][rt][v] = q[c][rt][v];
    int ps = e + 2; if (ps > STEPS - 1) ps = STEPS - 1;
#pragma unroll
    for (int c = 0; c < NCH; c++)
#pragma unroll
      for (int rt = 0; rt < 2; rt++)
        pf[cur][c][rt] = loadp(c, ps, rb[rt], false);
    lds_barrier();
  };

  for (int e = 0; e < BURN; e += 2) {        // BURN even
    burn_body(e, 0, 1);
    burn_body(e + 1, 1, 0);
  }
  for (int e = BURN; e < STEPS; e += 2) {    // STEPS even
    main_body(e, 0, 1);
    main_body(e + 1, 1, 0);
  }

  // --- tail: finalize epoch STEPS-1 (partials in pZL[(STEPS-1)&1]=pZL[1])
#pragma unroll
  for (int c = 0; c < NCH; c++) {
    float Z = 0.f, L = 0.f;
#pragma unroll
    for (int g = 0; g < 32; g++) {
      f32x2 v = pZL[1][c][g][n];
      Z += v[0]; L += v[1];
    }
    const float zi = __builtin_amdgcn_rcpf(Z);
    const int t1 = (cbase + c * G + n) * CLEN + (CLEN - 1);
#pragma unroll
    for (int rt = 0; rt < 2; rt++) {
      f32x4 o;
#pragma unroll
      for (int v = 0; v < 4; v++) o[v] = qp[c][rt][v] * zi;
      __builtin_nontemporal_store(
          o, reinterpret_cast<f32x4*>(out + (size_t)t1 * DIM + rb[rt]));
    }
    if (lane < 16 && w == c * 4)
      __builtin_nontemporal_store(__logf(Z) - L * zi,
                                  out + (size_t)SEQ * DIM + t1);
  }
}

extern "C" void kernel_launch(void* const* d_in, const int* in_sizes, int n_in,
                              void* d_out, int out_size, void* d_ws, size_t ws_size,
                              hipStream_t stream) {
  const float* probs = (const float*)d_in[0];   // (65536, 256)
  const float* tp    = (const float*)d_in[1];   // (256, 256)
  float* out         = (float*)d_out;           // 65536*256 probs + 65536 H

  hipLaunchKernelGGL(prior_scan_kernel, dim3(NBLK), dim3(TPB), 0, stream,
                     probs, tp, out);
}

// Round 4
// 134.266 us; speedup vs baseline: 1.0962x; 1.0962x over previous
//
#include <hip/hip_runtime.h>
#include <hip/hip_bf16.h>
#include <stdint.h>

// ===================================================================
// PriorLayer online BP scan, round 6. s_t = norm(diag(p_t) T s_{t-1}).
// Evidence R2-R5: per-matvec cost pinned ~4100-5700 cyc under all
// structural changes; no pipe >31%; epoch time = SUM of serial terms
// (LDS queue + MFMA chains + shuffles + finalize reads + epilogue +
// barrier), not one dominator. R4 reinterpreted: no spills (FETCH
// unchanged; A[4][8] lives in AGPRs) -- fewer waves/SIMD genuinely
// hurt. R5: +ILP = only -13%/matvec, and its 512 finalize broadcasts
// were a hidden cost. Strategy: best skeleton (R2) + cut every term:
//  - BURN 12 -> 8: 24 epochs (-14%). Contraction ~0.04/step => burn
//    truncation ~1e-11 << bf16 floor (absmax = 2^-5 is quantization).
//  - No cross-lane ops on the chain: lane-private partials (R4/R5
//    validated), pZL layout [buf][n][g] (+pad) => finalize = 4x
//    ds_read_b128 per wave + 2 deferred shfl_xor pairs.
//  - 4 MFMA chains of depth 4 (serial MFMA ~80 cyc).
//  - Prefetch issued right after B-reads (max vmem slack).
//  - Plain stores (NT caused +8-23MB HBM write amplification).
// ===================================================================

#define DIM   256
#define SEQ   65536
#define G     16                    // chunks (MFMA columns) per block
#define CLEN  16                    // output steps per chunk
#define NBLK  (SEQ / (G * CLEN))    // 256 blocks -> 1 per CU
#define BURN  8
#define STEPS (BURN + CLEN)         // 24 (even — pairing relies on it)
#define NW    8
#define TPB   (NW * 64)             // 512
#define SROW  264                   // padded LDS row stride (bf16 elems)
#define PG    34                    // padded group stride for pZL (f32x2)

typedef short bf16x8 __attribute__((ext_vector_type(8)));
typedef float f32x4  __attribute__((ext_vector_type(4)));
typedef float f32x2  __attribute__((ext_vector_type(2)));

static __device__ __forceinline__ unsigned short f2bf(float x) {
  __hip_bfloat16 h = __float2bfloat16(x);
  return *reinterpret_cast<unsigned short*>(&h);
}

// LDS-only barrier: do NOT drain vmcnt (global stores / prefetch loads
// stay in flight). lgkmcnt(0) orders all ds ops.
static __device__ __forceinline__ void lds_barrier() {
  asm volatile("s_waitcnt lgkmcnt(0)" ::: "memory");
  __builtin_amdgcn_s_barrier();
}

__global__ __launch_bounds__(TPB)
void prior_scan_kernel(const float* __restrict__ probs,
                       const float* __restrict__ tp,
                       float* __restrict__ out) {
  // S_T: double-buffered transposed state [buf][chunk][row] (bf16).
  // pZL: double-buffered lane partials [buf][n][group g=w*4+quad].
  //      n-stride 34*8B=272B (68 dw, %32=4): write 2-way banks (free),
  //      finalize b128 reads 4-way (1.58x, 4 instrs -- cheap).
  __shared__ __attribute__((aligned(16))) short S_T[2][G][SROW];
  __shared__ __attribute__((aligned(16))) f32x2 pZL[2][G][PG];

  const int tid  = threadIdx.x;
  const int w    = tid >> 6;
  const int lane = tid & 63;
  const int n    = lane & 15;       // MFMA col = chunk within block
  const int quad = lane >> 4;
  const int cbase = blockIdx.x * G;
  const int g  = w * 4 + quad;      // lane's row-group id (0..31)
  const int rb0 = w * 32 + quad * 4;        // C/D row base, tile 0
  const int rb1 = w * 32 + 16 + quad * 4;   // row-tile 1

  // ---- T into A-fragments: A[m=lane&15][k=quad*8+j]; row=w*32+rt*16+m
  bf16x8 A[2][8];
#pragma unroll
  for (int rt = 0; rt < 2; rt++) {
    const int row = w * 32 + rt * 16 + n;
#pragma unroll
    for (int kb = 0; kb < 8; kb++) {
      const float* p = tp + row * DIM + kb * 32 + quad * 8;
      f32x4 f0 = *reinterpret_cast<const f32x4*>(p);
      f32x4 f1 = *reinterpret_cast<const f32x4*>(p + 4);
      bf16x8 a;
#pragma unroll
      for (int j = 0; j < 4; j++) {
        a[j]     = (short)f2bf(f0[j]);
        a[4 + j] = (short)f2bf(f1[j]);
      }
      A[rt][kb] = a;
    }
  }

  // ---- init state buf 0 = uniform 1/256 (bf16-exact; scale-invariant)
  for (int i = tid; i < G * SROW; i += TPB)
    (&S_T[0][0][0])[i] = (short)0x3B80;

  // ---- observation fragment loader (lane-owned, direct from global)
  auto loadp = [&](int s, int rbase, bool clamp) -> f32x4 {
    int t = (cbase + n) * CLEN - BURN + s;
    if (clamp && t < 0) t = 0;      // value unused when t<0
    return *reinterpret_cast<const f32x4*>(probs + (size_t)t * DIM + rbase);
  };

  // 2-deep register prefetch ring
  f32x4 pf[2][2];
  pf[0][0] = loadp(0, rb0, true); pf[0][1] = loadp(0, rb1, true);
  pf[1][0] = loadp(1, rb0, true); pf[1][1] = loadp(1, rb1, true);

  lds_barrier();

  float qp[2][4];                   // q of previous epoch (deferred norm)

  // --- recurrence core: q = (T @ u) .* p  (4 chains of depth 4)
  auto matvec = [&](int cur, float (&q)[2][4]) {
    f32x4 aE0 = {0.f,0.f,0.f,0.f}, aO0 = {0.f,0.f,0.f,0.f};
    f32x4 aE1 = {0.f,0.f,0.f,0.f}, aO1 = {0.f,0.f,0.f,0.f};
#pragma unroll
    for (int kb = 0; kb < 8; kb += 2) {
      bf16x8 b0 = *reinterpret_cast<const bf16x8*>(
          &S_T[cur][n][kb * 32 + quad * 8]);
      bf16x8 b1 = *reinterpret_cast<const bf16x8*>(
          &S_T[cur][n][(kb + 1) * 32 + quad * 8]);
      aE0 = __builtin_amdgcn_mfma_f32_16x16x32_bf16(A[0][kb],     b0, aE0, 0, 0, 0);
      aE1 = __builtin_amdgcn_mfma_f32_16x16x32_bf16(A[1][kb],     b0, aE1, 0, 0, 0);
      aO0 = __builtin_amdgcn_mfma_f32_16x16x32_bf16(A[0][kb + 1], b1, aO0, 0, 0, 0);
      aO1 = __builtin_amdgcn_mfma_f32_16x16x32_bf16(A[1][kb + 1], b1, aO1, 0, 0, 0);
    }
    f32x4 p0 = pf[cur][0], p1 = pf[cur][1];
#pragma unroll
    for (int v = 0; v < 4; v++) {
      q[0][v] = (aE0[v] + aO0[v]) * p0[v];  // C/D: row=quad*4+v, col=n
      q[1][v] = (aE1[v] + aO1[v]) * p1[v];
    }
  };

  auto write_state = [&](int nxt, const float (&q)[2][4]) {
    ushort4 s0, s1;
    s0.x = f2bf(q[0][0] * 0.015625f); s0.y = f2bf(q[0][1] * 0.015625f);
    s0.z = f2bf(q[0][2] * 0.015625f); s0.w = f2bf(q[0][3] * 0.015625f);
    s1.x = f2bf(q[1][0] * 0.015625f); s1.y = f2bf(q[1][1] * 0.015625f);
    s1.z = f2bf(q[1][2] * 0.015625f); s1.w = f2bf(q[1][3] * 0.015625f);
    *reinterpret_cast<ushort4*>(&S_T[nxt][n][rb0]) = s0;
    *reinterpret_cast<ushort4*>(&S_T[nxt][n][rb1]) = s1;
  };

  // --- deferred finalize of epoch e1 (partials in pZL[pbuf])
  auto finalize = [&](int pbuf, int e1) {
    const f32x4* base = reinterpret_cast<const f32x4*>(&pZL[pbuf][n][quad * 8]);
    f32x4 r0 = base[0], r1 = base[1], r2 = base[2], r3 = base[3];
    float Z = (r0[0] + r0[2]) + (r1[0] + r1[2]) +
              (r2[0] + r2[2]) + (r3[0] + r3[2]);
    float L = (r0[1] + r0[3]) + (r1[1] + r1[3]) +
              (r2[1] + r2[3]) + (r3[1] + r3[3]);
    Z += __shfl_xor(Z, 16); Z += __shfl_xor(Z, 32);
    L += __shfl_xor(L, 16); L += __shfl_xor(L, 32);
    const float zi = __builtin_amdgcn_rcpf(Z);
    const int t1 = (cbase + n) * CLEN + (e1 - BURN);
    f32x4 o0, o1;
#pragma unroll
    for (int v = 0; v < 4; v++) { o0[v] = qp[0][v] * zi; o1[v] = qp[1][v] * zi; }
    *reinterpret_cast<f32x4*>(out + (size_t)t1 * DIM + rb0) = o0;
    *reinterpret_cast<f32x4*>(out + (size_t)t1 * DIM + rb1) = o1;
    if (tid < 16)                   // n == tid for these lanes
      out[(size_t)SEQ * DIM + t1] = __logf(Z) - L * zi;
  };

  // --- burn epoch: NO partials, NO finalize, NO qp carry
  auto burn_body = [&](int e, int cur, int nxt) {
    float q[2][4];
    matvec(cur, q);
    pf[cur][0] = loadp(e + 2, rb0, true);   // issue early; e+2 <= BURN+1
    pf[cur][1] = loadp(e + 2, rb1, true);
    const int t = (cbase + n) * CLEN - BURN + e;
    if (t < 0) {                    // pre-start: hold uniform state
      ushort4 sp;
      sp.x = sp.y = sp.z = sp.w = (unsigned short)0x3B80;
      *reinterpret_cast<ushort4*>(&S_T[nxt][n][rb0]) = sp;
      *reinterpret_cast<ushort4*>(&S_T[nxt][n][rb1]) = sp;
    } else {
      write_state(nxt, q);
    }
    lds_barrier();
  };

  // --- output epoch: lane-private partials + deferred finalize of e-1
  auto main_body = [&](int e, int cur, int nxt) {
    float q[2][4];
    matvec(cur, q);
    int ps = e + 2; if (ps > STEPS - 1) ps = STEPS - 1;   // t >= 2-BURN.. fine
    pf[cur][0] = loadp(ps, rb0, false);     // issue early (vmem slack)
    pf[cur][1] = loadp(ps, rb1, false);
    write_state(nxt, q);

    // lane-private partial over this lane's 8 rows (no cross-lane ops)
    float sz = 0.f, sl = 0.f;
#pragma unroll
    for (int rt = 0; rt < 2; rt++)
#pragma unroll
      for (int v = 0; v < 4; v++) {
        float qq = q[rt][v];
        sz += qq;
        sl += qq * __logf(qq + 1e-30f);
      }
    pZL[cur][n][g] = f32x2{sz, sl};

    if (e > BURN) finalize(nxt, e - 1);     // nxt == (e-1)&1

#pragma unroll
    for (int rt = 0; rt < 2; rt++)
#pragma unroll
      for (int v = 0; v < 4; v++) qp[rt][v] = q[rt][v];
    lds_barrier();
  };

  for (int e = 0; e < BURN; e += 2) {        // BURN even
    burn_body(e, 0, 1);
    burn_body(e + 1, 1, 0);
  }
  for (int e = BURN; e < STEPS; e += 2) {    // STEPS even, BURN even
    main_body(e, 0, 1);
    main_body(e + 1, 1, 0);
  }

  // --- tail: finalize epoch STEPS-1 (partials in pZL[(STEPS-1)&1])
  finalize((STEPS - 1) & 1, STEPS - 1);
}

extern "C" void kernel_launch(void* const* d_in, const int* in_sizes, int n_in,
                              void* d_out, int out_size, void* d_ws, size_t ws_size,
                              hipStream_t stream) {
  const float* probs = (const float*)d_in[0];   // (65536, 256)
  const float* tp    = (const float*)d_in[1];   // (256, 256)
  float* out         = (float*)d_out;           // 65536*256 probs + 65536 H

  hipLaunchKernelGGL(prior_scan_kernel, dim3(NBLK), dim3(TPB), 0, stream,
                     probs, tp, out);
}